// Round 9
// baseline (380.169 us; speedup 1.0000x reference)
//
#include <hip/hip_runtime.h>
#include <math.h>
#include <stdint.h>

#define NB 32
#define NQ 4000
#define NG 100
#define NC1 4
#define NC2 32
#define NC3 8
#define NCT 44   // NC1+NC2+NC3
#define GCH 25   // g-chunk per cost block (NG/4)

// output layout (floats): m[B,Q,G] | selected[B,Q] | gt_idx[B,Q] | matched_qidx[B,G] | cost[B,Q,G]
static const size_t OFF_M    = 0;
static const size_t OFF_SEL  = (size_t)NB * NQ * NG;          // 12,800,000
static const size_t OFF_GTI  = OFF_SEL + (size_t)NB * NQ;     // 12,928,000
static const size_t OFF_MQ   = OFF_GTI + (size_t)NB * NQ;     // 13,056,000
static const size_t OFF_COST = OFF_MQ + (size_t)NB * NG;      // 13,059,200

__device__ __forceinline__ float focal_diff(float x) {
    float p   = 1.0f / (1.0f + expf(-x));
    float neg = 0.75f * (p * p) * (-logf(1.0f - p + 1e-8f));
    float pos = 0.25f * ((1.0f - p) * (1.0f - p)) * (-logf(p + 1e-8f));
    return pos - neg;
}

// ---------------- focal kernel: FDT[b][c][q] (c-major) via LDS tile transpose ----------------
__global__ __launch_bounds__(256) void focal_kernel(
    const float* __restrict__ l1, const float* __restrict__ l2, const float* __restrict__ l3,
    float* __restrict__ FDT)
{
    const int b  = blockIdx.y;
    const int q0 = blockIdx.x * 64;
    const int tid = threadIdx.x;
    __shared__ float tile[64][NCT + 1];   // stride 45 (odd) -> conflict-free column reads

    for (int idx = tid; idx < 64 * NC1; idx += 256) {
        const int qi = idx >> 2, c = idx & 3;
        const int q = q0 + qi;
        if (q < NQ) tile[qi][c] = focal_diff(l1[((size_t)b * NQ + q) * NC1 + c]);
    }
    for (int idx = tid; idx < 64 * NC2; idx += 256) {
        const int qi = idx >> 5, c = idx & 31;
        const int q = q0 + qi;
        if (q < NQ) tile[qi][NC1 + c] = focal_diff(l2[((size_t)b * NQ + q) * NC2 + c]);
    }
    for (int idx = tid; idx < 64 * NC3; idx += 256) {
        const int qi = idx >> 3, c = idx & 7;
        const int q = q0 + qi;
        if (q < NQ) tile[qi][NC1 + NC2 + c] = focal_diff(l3[((size_t)b * NQ + q) * NC3 + c]);
    }
    __syncthreads();

    for (int idx = tid; idx < NCT * 64; idx += 256) {
        const int c = idx >> 6, qi = idx & 63;
        const int q = q0 + qi;
        if (q < NQ) FDT[((size_t)b * NCT + c) * NQ + q] = tile[qi][c];
    }
}

// ---------------- mask kernel: gating masks per (b,q): bm uint4 + fgadd ----------------
__global__ __launch_bounds__(256) void mask_kernel(
    const float* __restrict__ pb, const float* __restrict__ gbx,
    uint4* __restrict__ bmout, float* __restrict__ fgout)
{
    const int b   = blockIdx.y;
    const int tid = threadIdx.x;

    __shared__ float s_ib[NG][4];   // round-tripped xyxy for in_box
    __shared__ float s_ic[NG][4];   // center-radius bounds

    if (tid < NG) {
        const int g = tid;
        const float x0 = gbx[((size_t)b * NG + g) * 4 + 0];
        const float y0 = gbx[((size_t)b * NG + g) * 4 + 1];
        const float x1 = gbx[((size_t)b * NG + g) * 4 + 2];
        const float y1 = gbx[((size_t)b * NG + g) * 4 + 3];
        const float cx = (x0 + x1) * 0.5f, cy = (y0 + y1) * 0.5f;
        const float w0 = x1 - x0, h0 = y1 - y0;
        const float bx0 = cx - 0.5f * w0, bx1 = cx + 0.5f * w0;
        const float by0 = cy - 0.5f * h0, by1 = cy + 0.5f * h0;
        s_ib[g][0] = bx0; s_ib[g][1] = by0; s_ib[g][2] = bx1; s_ib[g][3] = by1;
        const float w = bx1 - bx0, h = by1 - by0;   // reference recomputes w,h from round-tripped xyxy
        s_ic[g][0] = cx - 2.5f * w; s_ic[g][1] = cx + 2.5f * w;
        s_ic[g][2] = cy - 2.5f * h; s_ic[g][3] = cy + 2.5f * h;
    }
    __syncthreads();

    const int q = blockIdx.x * 256 + tid;
    if (q >= NQ) return;

    const float4 pv = reinterpret_cast<const float4*>(pb)[(size_t)b * NQ + q];
    const float ax = (pv.x + pv.z) * 0.5f, ay = (pv.y + pv.w) * 0.5f;

    unsigned bm[4] = {0u, 0u, 0u, 0u};
    bool fg = false;
    for (int g = 0; g < NG; ++g) {
        const bool ib = (ax > s_ib[g][0]) && (ax < s_ib[g][2]) && (ay > s_ib[g][1]) && (ay < s_ib[g][3]);
        const bool ic = (ax > s_ic[g][0]) && (ax < s_ic[g][1]) && (ay > s_ic[g][2]) && (ay < s_ic[g][3]);
        fg = fg || ib || ic;
        if (ib && ic) bm[g >> 5] |= (1u << (g & 31));
    }
    bmout[(size_t)b * NQ + q] = make_uint4(bm[0], bm[1], bm[2], bm[3]);
    fgout[(size_t)b * NQ + q] = fg ? 0.0f : 10000.0f;
}

// ---------------- cost kernel: grid (qblocks, B, 4 g-chunks), one thread per q ----------------
__global__ __launch_bounds__(256) void cost_kernel(
    const float* __restrict__ pb, const float* __restrict__ gbx, const float* __restrict__ img,
    const int* __restrict__ t1, const int* __restrict__ t2, const int* __restrict__ t3,
    const float* __restrict__ FDT, const uint4* __restrict__ bmin, const float* __restrict__ fgin,
    float* __restrict__ costT)
{
    const int b   = blockIdx.y;
    const int g0  = blockIdx.z * GCH;
    const int tid = threadIdx.x;

    __shared__ float s_ng[GCH][4];
    __shared__ float s_gx[GCH][4];
    __shared__ float s_ab[GCH];
    __shared__ int   s_lab[GCH][3];
    __shared__ float s_isz[4];

    if (tid < 4) s_isz[tid] = img[b * 4 + tid];
    if (tid < GCH) {
        const int g = g0 + tid;
        const float x0 = gbx[((size_t)b * NG + g) * 4 + 0];
        const float y0 = gbx[((size_t)b * NG + g) * 4 + 1];
        const float x1 = gbx[((size_t)b * NG + g) * 4 + 2];
        const float y1 = gbx[((size_t)b * NG + g) * 4 + 3];
        s_gx[tid][0] = x0; s_gx[tid][1] = y0; s_gx[tid][2] = x1; s_gx[tid][3] = y1;
        s_ab[tid] = (x1 - x0) * (y1 - y0);
        s_ng[tid][0] = x0 / img[b * 4 + 0];
        s_ng[tid][1] = y0 / img[b * 4 + 1];
        s_ng[tid][2] = x1 / img[b * 4 + 2];
        s_ng[tid][3] = y1 / img[b * 4 + 3];
        s_lab[tid][0] = t1[b * NG + g];
        s_lab[tid][1] = NC1 + t2[b * NG + g];
        s_lab[tid][2] = NC1 + NC2 + t3[b * NG + g];
    }
    __syncthreads();

    const int q = blockIdx.x * 256 + tid;
    if (q >= NQ) return;

    const float4 pv = reinterpret_cast<const float4*>(pb)[(size_t)b * NQ + q];
    const float p0 = pv.x, p1 = pv.y, p2 = pv.z, p3 = pv.w;
    const float areaA = (p2 - p0) * (p3 - p1);
    const float n0 = p0 / s_isz[0], n1 = p1 / s_isz[1], n2 = p2 / s_isz[2], n3 = p3 / s_isz[3];

    const uint4 bm4 = bmin[(size_t)b * NQ + q];
    const unsigned bm[4] = {bm4.x, bm4.y, bm4.z, bm4.w};
    const float fgadd = fgin[(size_t)b * NQ + q];

    const float* F = FDT + (size_t)b * NCT * NQ + q;
    float* ct = costT + (size_t)b * NG * NQ + q + (size_t)g0 * NQ;
#pragma unroll 5
    for (int gl = 0; gl < GCH; ++gl) {
        const int g = g0 + gl;
        const float f1 = F[(size_t)s_lab[gl][0] * NQ];
        const float f2 = F[(size_t)s_lab[gl][1] * NQ];
        const float f3 = F[(size_t)s_lab[gl][2] * NQ];
        float cb = fabsf(n0 - s_ng[gl][0]);
        cb = cb + fabsf(n1 - s_ng[gl][1]);
        cb = cb + fabsf(n2 - s_ng[gl][2]);
        cb = cb + fabsf(n3 - s_ng[gl][3]);
        const float gx0 = s_gx[gl][0], gy0 = s_gx[gl][1], gx1 = s_gx[gl][2], gy1 = s_gx[gl][3];
        const float ltx = fmaxf(p0, gx0), lty = fmaxf(p1, gy0);
        const float rbx = fminf(p2, gx1), rby = fminf(p3, gy1);
        const float iw = fmaxf(rbx - ltx, 0.0f), ih = fmaxf(rby - lty, 0.0f);
        const float inter = iw * ih;
        const float uni = areaA + s_ab[gl] - inter;
        const float iou = inter / uni;
        const float ex0 = fminf(p0, gx0), ey0 = fminf(p1, gy0);
        const float ex1 = fmaxf(p2, gx1), ey1 = fmaxf(p3, gy1);
        const float ew = fmaxf(ex1 - ex0, 0.0f), eh = fmaxf(ey1 - ey0, 0.0f);
        const float ea = ew * eh;
        const float giou = iou - (ea - uni) / ea;
        const float cc = (f1 + f2) + f3;
        const bool inbc = (bm[g >> 5] >> (g & 31)) & 1u;
        float cost = cb;
        cost = cost + 0.33333334f * cc;
        cost = cost + (-giou);
        cost = cost + (inbc ? 0.0f : 100.0f);
        cost = cost + fgadd;
        ct[(size_t)gl * NQ] = cost;
    }
}

// ---------------- top-5 helpers (round-5 validated) ----------------
template <bool MAXSEL>
__device__ __forceinline__ bool better(float av, int ai, float bv, int bi) {
    if (MAXSEL) return (av > bv) || (av == bv && ai < bi);
    else        return (av < bv) || (av == bv && ai < bi);
}

template <bool MAXSEL>
__device__ __forceinline__ void ins5(float (&v)[5], int (&id)[5], float nv, int ni) {
    if (!better<MAXSEL>(nv, ni, v[4], id[4])) return;
    v[4] = nv; id[4] = ni;
#pragma unroll
    for (int j = 4; j > 0; --j) {
        if (better<MAXSEL>(v[j], id[j], v[j - 1], id[j - 1])) {
            float tv = v[j]; v[j] = v[j - 1]; v[j - 1] = tv;
            int   ti = id[j]; id[j] = id[j - 1]; id[j - 1] = ti;
        }
    }
}

template <bool MAXSEL>
__device__ __forceinline__ void merge5(float (&v)[5], int (&id)[5], float (&ov)[5], int (&oi)[5]) {
#pragma unroll
    for (int r = 0; r < 5; ++r) {
        float bv = v[0]; int bi = id[0];
#pragma unroll
        for (int off = 32; off >= 1; off >>= 1) {
            float xv = __shfl_xor(bv, off, 64);
            int   xi = __shfl_xor(bi, off, 64);
            if (better<MAXSEL>(xv, xi, bv, bi)) { bv = xv; bi = xi; }
        }
        ov[r] = bv; oi[r] = bi;
        if (id[0] == bi) {
            v[0] = v[1]; id[0] = id[1];
            v[1] = v[2]; id[1] = id[2];
            v[2] = v[3]; id[2] = id[3];
            v[3] = v[4]; id[3] = id[4];
            v[4] = MAXSEL ? -INFINITY : INFINITY; id[4] = 0x7fffffff;
        }
    }
}

// ---------------- per-column top-5 (round-5 validated, 4 waves/column) ----------------
#define CHUNK 1000   // NQ / 4
__global__ __launch_bounds__(256) void col_topk_kernel(
    const float* __restrict__ pb, const float* __restrict__ gbx, const float* __restrict__ costT,
    int* __restrict__ grc, int* __restrict__ grnew)
{
    const int g = blockIdx.x, b = blockIdx.y;
    const int tid = threadIdx.x, lane = tid & 63, wave = tid >> 6;   // 4 waves

    __shared__ float s_v[2][4][5];
    __shared__ int   s_i[2][4][5];

    const float gx0 = gbx[((size_t)b * NG + g) * 4 + 0];
    const float gy0 = gbx[((size_t)b * NG + g) * 4 + 1];
    const float gx1 = gbx[((size_t)b * NG + g) * 4 + 2];
    const float gy1 = gbx[((size_t)b * NG + g) * 4 + 3];
    const float areaB = (gx1 - gx0) * (gy1 - gy0);
    const float4* PB = reinterpret_cast<const float4*>(pb) + (size_t)b * NQ;
    const float* CT = costT + (size_t)b * NG * NQ + (size_t)g * NQ;

    const int q0 = wave * CHUNK, q1 = q0 + CHUNK;

    // IoU top-5 over this wave's chunk
    {
        float tv[5]; int ti[5];
#pragma unroll
        for (int k = 0; k < 5; ++k) { tv[k] = -INFINITY; ti[k] = 0x7fffffff; }
        for (int base = q0; base < q1; base += 64) {
            const int q = base + lane;
            if (q < q1) {
                const float4 p = PB[q];
                const float ltx = fmaxf(p.x, gx0), lty = fmaxf(p.y, gy0);
                const float rbx = fminf(p.z, gx1), rby = fminf(p.w, gy1);
                const float iw = fmaxf(rbx - ltx, 0.0f), ih = fmaxf(rby - lty, 0.0f);
                const float inter = iw * ih;
                const float areaA = (p.z - p.x) * (p.w - p.y);
                const float uni = areaA + areaB - inter;
                ins5<true>(tv, ti, inter / uni, q);
            }
        }
        float ov[5]; int oi[5];
        merge5<true>(tv, ti, ov, oi);
        if (lane == 0) {
#pragma unroll
            for (int k = 0; k < 5; ++k) { s_v[0][wave][k] = ov[k]; s_i[0][wave][k] = oi[k]; }
        }
    }

    // cost top-5 (min) over this wave's chunk
    {
        float tv[5]; int ti[5];
#pragma unroll
        for (int k = 0; k < 5; ++k) { tv[k] = INFINITY; ti[k] = 0x7fffffff; }
        for (int base = q0; base < q1; base += 64) {
            const int q = base + lane;
            if (q < q1) ins5<false>(tv, ti, CT[q], q);
        }
        float ov[5]; int oi[5];
        merge5<false>(tv, ti, ov, oi);
        if (lane == 0) {
#pragma unroll
            for (int k = 0; k < 5; ++k) { s_v[1][wave][k] = ov[k]; s_i[1][wave][k] = oi[k]; }
        }
    }
    __syncthreads();

    if (tid == 0) {
        float tv[5]; int ti[5];
#pragma unroll
        for (int k = 0; k < 5; ++k) { tv[k] = -INFINITY; ti[k] = 0x7fffffff; }
        for (int w = 0; w < 4; ++w)
#pragma unroll
            for (int k = 0; k < 5; ++k) ins5<true>(tv, ti, s_v[0][w][k], s_i[0][w][k]);
        const float s = ((((tv[0] + tv[1]) + tv[2]) + tv[3]) + tv[4]);
        int dk = (int)s;   // trunc toward zero, matches astype(int32)
        if (dk < 1) dk = 1;

        float cv[5]; int ci[5];
#pragma unroll
        for (int k = 0; k < 5; ++k) { cv[k] = INFINITY; ci[k] = 0x7fffffff; }
        for (int w = 0; w < 4; ++w)
#pragma unroll
            for (int k = 0; k < 5; ++k) ins5<false>(cv, ci, s_v[1][w][k], s_i[1][w][k]);

        for (int k = 0; k < dk; ++k) {
            atomicAdd(&grc[b * NQ + ci[k]], 1);
            grnew[b * NQ + ci[k]] = g;   // benign race: only read when grc==1
        }
    }
}

// replicate reference's sequential penalty accumulation rounding
__device__ __forceinline__ float pen_add(float v, int k) {
    while (k-- > 0) v += 100000.0f;
    return v;
}

__device__ __forceinline__ unsigned ordered_bits(float f) {
    unsigned u = __float_as_uint(f);
    return (u & 0x80000000u) ? ~u : (u | 0x80000000u);
}

// ---------------- match kernel: one block per image, only the sequential loop ----------------
__global__ __launch_bounds__(1024) void match_kernel(
    const float* __restrict__ costT, const int* __restrict__ grc, const int* __restrict__ grnew,
    float* __restrict__ out, int* __restrict__ rm_out)
{
    const int b = blockIdx.x, tid = threadIdx.x;
    const int lane = tid & 63, wave = tid >> 6;   // 16 waves

    __shared__ short              rmatch[NQ];
    __shared__ short              rnew[NQ];
    __shared__ unsigned short     pen[NQ];
    __shared__ int                rc[NQ];
    __shared__ int                colc[NG];
    __shared__ unsigned long long colkey[NG];
    __shared__ int                flag;

    const float* CT = costT + (size_t)b * NG * NQ;

    for (int q = tid; q < NQ; q += 1024) {
        rmatch[q] = -1;
        pen[q] = 0;
        rc[q] = grc[b * NQ + q];
        rnew[q] = (short)grnew[b * NQ + q];
    }
    __syncthreads();

    for (int iter = 0; iter < 2000; ++iter) {
        for (int q = tid; q < NQ; q += 1024) {
            const int oldm = rmatch[q];
            const int rcq  = rc[q];
            const int c    = rcq + (oldm >= 0 ? 1 : 0);
            int nm;
            if (c == 0) nm = -1;
            else if (c == 1) nm = rcq ? (int)rnew[q] : oldm;
            else {
                const int kp = pen[q];
                float bv = INFINITY; nm = 0;
                for (int g = 0; g < NG; ++g) {
                    const float v = pen_add(CT[(size_t)g * NQ + q], kp);
                    if (v < bv) { bv = v; nm = g; }
                }
            }
            rmatch[q] = (short)nm; rc[q] = 0;
        }
        __syncthreads();
        if (tid < NG) colc[tid] = 0;
        if (tid == 0) flag = 0;
        __syncthreads();
        for (int q = tid; q < NQ; q += 1024) { const int m = rmatch[q]; if (m >= 0) atomicAdd(&colc[m], 1); }
        __syncthreads();
        if (tid < NG && colc[tid] == 0) flag = 1;
        __syncthreads();
        if (!flag) break;

        for (int q = tid; q < NQ; q += 1024) { if (rmatch[q] >= 0) pen[q]++; }
        __syncthreads();
        for (int g = wave; g < NG; g += 16) {
            if (colc[g] != 0) continue;
            float bv = INFINITY; int bi = 0x7fffffff;
            for (int base = 0; base < NQ; base += 64) {
                const int q = base + lane;
                if (q < NQ) {
                    const float v = pen_add(CT[(size_t)g * NQ + q], (int)pen[q]);
                    if (v < bv || (v == bv && q < bi)) { bv = v; bi = q; }
                }
            }
#pragma unroll
            for (int off = 32; off >= 1; off >>= 1) {
                const float xv = __shfl_xor(bv, off, 64);
                const int   xi = __shfl_xor(bi, off, 64);
                if (xv < bv || (xv == bv && xi < bi)) { bv = xv; bi = xi; }
            }
            if (lane == 0) { atomicAdd(&rc[bi], 1); rnew[bi] = (short)g; }
        }
        __syncthreads();
    }

    // outputs: selected, gt_idx, rm; matched_qidx via per-row atomicMin (ordered-float<<32 | q)
    if (tid < NG) colkey[tid] = ~0ull;
    __syncthreads();
    for (int q = tid; q < NQ; q += 1024) {
        const int m = rmatch[q];
        out[OFF_SEL + (size_t)b * NQ + q] = (m >= 0) ? 1.0f : 0.0f;
        out[OFF_GTI + (size_t)b * NQ + q] = (float)(m >= 0 ? m : 0);
        rm_out[b * NQ + q] = m;
        if (m >= 0) {
            const float v = pen_add(CT[(size_t)m * NQ + q], (int)pen[q]);
            const unsigned long long key = ((unsigned long long)ordered_bits(v) << 32) | (unsigned)q;
            atomicMin(&colkey[m], key);
        }
    }
    __syncthreads();
    if (tid < NG) out[OFF_MQ + (size_t)b * NG + tid] = (float)(unsigned)(colkey[tid] & 0xffffffffull);
}

// ---------------- write-out: cost transpose + m expansion in one pass ----------------
__global__ __launch_bounds__(256) void write_out_kernel(
    const float* __restrict__ costT, const int* __restrict__ rm, float* __restrict__ out)
{
    const int b  = blockIdx.y;
    const int q0 = blockIdx.x * 64;
    __shared__ float tile[NG][65];
    __shared__ short srm[64];
    const float* CT = costT + (size_t)b * NG * NQ;
    for (int idx = threadIdx.x; idx < NG * 64; idx += 256) {
        const int g = idx >> 6, qi = idx & 63;
        const int q = q0 + qi;
        if (q < NQ) tile[g][qi] = CT[(size_t)g * NQ + q];
    }
    if (threadIdx.x < 64) {
        const int q = q0 + threadIdx.x;
        srm[threadIdx.x] = (q < NQ) ? (short)rm[b * NQ + q] : (short)-1;
    }
    __syncthreads();
    float* OC = out + OFF_COST + (size_t)b * NQ * NG;
    float* OM = out + OFF_M    + (size_t)b * NQ * NG;
    for (int idx = threadIdx.x; idx < 64 * NG; idx += 256) {
        const int qi = idx / NG, g = idx - qi * NG;
        const int q = q0 + qi;
        if (q < NQ) {
            OC[(size_t)q * NG + g] = tile[g][qi];
            OM[(size_t)q * NG + g] = (srm[qi] == g) ? 1.0f : 0.0f;
        }
    }
}

extern "C" void kernel_launch(void* const* d_in, const int* in_sizes, int n_in,
                              void* d_out, int out_size, void* d_ws, size_t ws_size,
                              hipStream_t stream)
{
    const float* l1  = (const float*)d_in[0];
    const float* l2  = (const float*)d_in[1];
    const float* l3  = (const float*)d_in[2];
    const float* pb  = (const float*)d_in[3];
    const float* gbx = (const float*)d_in[4];
    const float* img = (const float*)d_in[5];
    const int*   t1  = (const int*)d_in[6];
    const int*   t2  = (const int*)d_in[7];
    const int*   t3  = (const int*)d_in[8];
    float* out = (float*)d_out;

    char* ws = (char*)d_ws;
    float* costT = (float*)ws;                                   ws += (size_t)NB * NG * NQ * sizeof(float); // 51.2 MB
    int*   rm    = (int*)ws;                                     ws += (size_t)NB * NQ * sizeof(int);
    int*   grc   = (int*)ws;                                     ws += (size_t)NB * NQ * sizeof(int);
    int*   grnew = (int*)ws;                                     ws += (size_t)NB * NQ * sizeof(int);
    uint4* bmws  = (uint4*)ws;                                   ws += (size_t)NB * NQ * sizeof(uint4);
    float* fgws  = (float*)ws;

    // FDT scratch lives in the cost-output region: written by focal_kernel, consumed
    // by cost_kernel, then overwritten by write_out_kernel. 22.5 MB < 51.2 MB region.
    float* FDT = out + OFF_COST;

    hipMemsetAsync(grc, 0, (size_t)NB * NQ * sizeof(int), stream);

    dim3 fg((NQ + 63) / 64, NB);
    focal_kernel<<<fg, 256, 0, stream>>>(l1, l2, l3, FDT);

    dim3 mk((NQ + 255) / 256, NB);
    mask_kernel<<<mk, 256, 0, stream>>>(pb, gbx, bmws, fgws);

    dim3 cg((NQ + 255) / 256, NB, 4);
    cost_kernel<<<cg, 256, 0, stream>>>(pb, gbx, img, t1, t2, t3, FDT, bmws, fgws, costT);

    dim3 kg(NG, NB);
    col_topk_kernel<<<kg, 256, 0, stream>>>(pb, gbx, costT, grc, grnew);

    match_kernel<<<NB, 1024, 0, stream>>>(costT, grc, grnew, out, rm);

    dim3 wg((NQ + 63) / 64, NB);
    write_out_kernel<<<wg, 256, 0, stream>>>(costT, rm, out);
}

// Round 10
// 364.948 us; speedup vs baseline: 1.0417x; 1.0417x over previous
//
#include <hip/hip_runtime.h>
#include <math.h>
#include <stdint.h>

#define NB 32
#define NQ 4000
#define NG 100
#define NC1 4
#define NC2 32
#define NC3 8
#define NCT 44   // NC1+NC2+NC3
#define GCH 25   // g-chunk per cost block (NG/4)

// output layout (floats): m[B,Q,G] | selected[B,Q] | gt_idx[B,Q] | matched_qidx[B,G] | cost[B,Q,G]
static const size_t OFF_M    = 0;
static const size_t OFF_SEL  = (size_t)NB * NQ * NG;          // 12,800,000
static const size_t OFF_GTI  = OFF_SEL + (size_t)NB * NQ;     // 12,928,000
static const size_t OFF_MQ   = OFF_GTI + (size_t)NB * NQ;     // 13,056,000
static const size_t OFF_COST = OFF_MQ + (size_t)NB * NG;      // 13,059,200

__device__ __forceinline__ float focal_diff(float x) {
    float p   = 1.0f / (1.0f + expf(-x));
    float neg = 0.75f * (p * p) * (-logf(1.0f - p + 1e-8f));
    float pos = 0.25f * ((1.0f - p) * (1.0f - p)) * (-logf(p + 1e-8f));
    return pos - neg;
}

// ---------------- focal kernel: FDT[b][c][q] (c-major) via LDS tile transpose ----------------
__global__ __launch_bounds__(256) void focal_kernel(
    const float* __restrict__ l1, const float* __restrict__ l2, const float* __restrict__ l3,
    float* __restrict__ FDT)
{
    const int b  = blockIdx.y;
    const int q0 = blockIdx.x * 64;
    const int tid = threadIdx.x;
    __shared__ float tile[64][NCT + 1];   // stride 45 (odd) -> conflict-free column reads

    for (int idx = tid; idx < 64 * NC1; idx += 256) {
        const int qi = idx >> 2, c = idx & 3;
        const int q = q0 + qi;
        if (q < NQ) tile[qi][c] = focal_diff(l1[((size_t)b * NQ + q) * NC1 + c]);
    }
    for (int idx = tid; idx < 64 * NC2; idx += 256) {
        const int qi = idx >> 5, c = idx & 31;
        const int q = q0 + qi;
        if (q < NQ) tile[qi][NC1 + c] = focal_diff(l2[((size_t)b * NQ + q) * NC2 + c]);
    }
    for (int idx = tid; idx < 64 * NC3; idx += 256) {
        const int qi = idx >> 3, c = idx & 7;
        const int q = q0 + qi;
        if (q < NQ) tile[qi][NC1 + NC2 + c] = focal_diff(l3[((size_t)b * NQ + q) * NC3 + c]);
    }
    __syncthreads();

    for (int idx = tid; idx < NCT * 64; idx += 256) {
        const int c = idx >> 6, qi = idx & 63;
        const int q = q0 + qi;
        if (q < NQ) FDT[((size_t)b * NCT + c) * NQ + q] = tile[qi][c];
    }
}

// ---------------- mask kernel: gating masks per (b,q): bm uint4 + fgadd ----------------
__global__ __launch_bounds__(256) void mask_kernel(
    const float* __restrict__ pb, const float* __restrict__ gbx,
    uint4* __restrict__ bmout, float* __restrict__ fgout)
{
    const int b   = blockIdx.y;
    const int tid = threadIdx.x;

    __shared__ float s_ib[NG][4];   // round-tripped xyxy for in_box
    __shared__ float s_ic[NG][4];   // center-radius bounds

    if (tid < NG) {
        const int g = tid;
        const float x0 = gbx[((size_t)b * NG + g) * 4 + 0];
        const float y0 = gbx[((size_t)b * NG + g) * 4 + 1];
        const float x1 = gbx[((size_t)b * NG + g) * 4 + 2];
        const float y1 = gbx[((size_t)b * NG + g) * 4 + 3];
        const float cx = (x0 + x1) * 0.5f, cy = (y0 + y1) * 0.5f;
        const float w0 = x1 - x0, h0 = y1 - y0;
        const float bx0 = cx - 0.5f * w0, bx1 = cx + 0.5f * w0;
        const float by0 = cy - 0.5f * h0, by1 = cy + 0.5f * h0;
        s_ib[g][0] = bx0; s_ib[g][1] = by0; s_ib[g][2] = bx1; s_ib[g][3] = by1;
        const float w = bx1 - bx0, h = by1 - by0;   // reference recomputes w,h from round-tripped xyxy
        s_ic[g][0] = cx - 2.5f * w; s_ic[g][1] = cx + 2.5f * w;
        s_ic[g][2] = cy - 2.5f * h; s_ic[g][3] = cy + 2.5f * h;
    }
    __syncthreads();

    const int q = blockIdx.x * 256 + tid;
    if (q >= NQ) return;

    const float4 pv = reinterpret_cast<const float4*>(pb)[(size_t)b * NQ + q];
    const float ax = (pv.x + pv.z) * 0.5f, ay = (pv.y + pv.w) * 0.5f;

    unsigned bm[4] = {0u, 0u, 0u, 0u};
    bool fg = false;
    for (int g = 0; g < NG; ++g) {
        const bool ib = (ax > s_ib[g][0]) && (ax < s_ib[g][2]) && (ay > s_ib[g][1]) && (ay < s_ib[g][3]);
        const bool ic = (ax > s_ic[g][0]) && (ax < s_ic[g][1]) && (ay > s_ic[g][2]) && (ay < s_ic[g][3]);
        fg = fg || ib || ic;
        if (ib && ic) bm[g >> 5] |= (1u << (g & 31));
    }
    bmout[(size_t)b * NQ + q] = make_uint4(bm[0], bm[1], bm[2], bm[3]);
    fgout[(size_t)b * NQ + q] = fg ? 0.0f : 10000.0f;
}

// ---------------- cost kernel: grid (qblocks, B, 4 g-chunks), one thread per q ----------------
__global__ __launch_bounds__(256) void cost_kernel(
    const float* __restrict__ pb, const float* __restrict__ gbx, const float* __restrict__ img,
    const int* __restrict__ t1, const int* __restrict__ t2, const int* __restrict__ t3,
    const float* __restrict__ FDT, const uint4* __restrict__ bmin, const float* __restrict__ fgin,
    float* __restrict__ costT)
{
    const int b   = blockIdx.y;
    const int g0  = blockIdx.z * GCH;
    const int tid = threadIdx.x;

    __shared__ float s_ng[GCH][4];
    __shared__ float s_gx[GCH][4];
    __shared__ float s_ab[GCH];
    __shared__ int   s_lab[GCH][3];
    __shared__ float s_isz[4];

    if (tid < 4) s_isz[tid] = img[b * 4 + tid];
    if (tid < GCH) {
        const int g = g0 + tid;
        const float x0 = gbx[((size_t)b * NG + g) * 4 + 0];
        const float y0 = gbx[((size_t)b * NG + g) * 4 + 1];
        const float x1 = gbx[((size_t)b * NG + g) * 4 + 2];
        const float y1 = gbx[((size_t)b * NG + g) * 4 + 3];
        s_gx[tid][0] = x0; s_gx[tid][1] = y0; s_gx[tid][2] = x1; s_gx[tid][3] = y1;
        s_ab[tid] = (x1 - x0) * (y1 - y0);
        s_ng[tid][0] = x0 / img[b * 4 + 0];
        s_ng[tid][1] = y0 / img[b * 4 + 1];
        s_ng[tid][2] = x1 / img[b * 4 + 2];
        s_ng[tid][3] = y1 / img[b * 4 + 3];
        s_lab[tid][0] = t1[b * NG + g];
        s_lab[tid][1] = NC1 + t2[b * NG + g];
        s_lab[tid][2] = NC1 + NC2 + t3[b * NG + g];
    }
    __syncthreads();

    const int q = blockIdx.x * 256 + tid;
    if (q >= NQ) return;

    const float4 pv = reinterpret_cast<const float4*>(pb)[(size_t)b * NQ + q];
    const float p0 = pv.x, p1 = pv.y, p2 = pv.z, p3 = pv.w;
    const float areaA = (p2 - p0) * (p3 - p1);
    const float n0 = p0 / s_isz[0], n1 = p1 / s_isz[1], n2 = p2 / s_isz[2], n3 = p3 / s_isz[3];

    const uint4 bm4 = bmin[(size_t)b * NQ + q];
    const unsigned bm[4] = {bm4.x, bm4.y, bm4.z, bm4.w};
    const float fgadd = fgin[(size_t)b * NQ + q];

    const float* F = FDT + (size_t)b * NCT * NQ + q;
    float* ct = costT + (size_t)b * NG * NQ + q + (size_t)g0 * NQ;
#pragma unroll 5
    for (int gl = 0; gl < GCH; ++gl) {
        const int g = g0 + gl;
        const float f1 = F[(size_t)s_lab[gl][0] * NQ];
        const float f2 = F[(size_t)s_lab[gl][1] * NQ];
        const float f3 = F[(size_t)s_lab[gl][2] * NQ];
        float cb = fabsf(n0 - s_ng[gl][0]);
        cb = cb + fabsf(n1 - s_ng[gl][1]);
        cb = cb + fabsf(n2 - s_ng[gl][2]);
        cb = cb + fabsf(n3 - s_ng[gl][3]);
        const float gx0 = s_gx[gl][0], gy0 = s_gx[gl][1], gx1 = s_gx[gl][2], gy1 = s_gx[gl][3];
        const float ltx = fmaxf(p0, gx0), lty = fmaxf(p1, gy0);
        const float rbx = fminf(p2, gx1), rby = fminf(p3, gy1);
        const float iw = fmaxf(rbx - ltx, 0.0f), ih = fmaxf(rby - lty, 0.0f);
        const float inter = iw * ih;
        const float uni = areaA + s_ab[gl] - inter;
        const float iou = inter / uni;
        const float ex0 = fminf(p0, gx0), ey0 = fminf(p1, gy0);
        const float ex1 = fmaxf(p2, gx1), ey1 = fmaxf(p3, gy1);
        const float ew = fmaxf(ex1 - ex0, 0.0f), eh = fmaxf(ey1 - ey0, 0.0f);
        const float ea = ew * eh;
        const float giou = iou - (ea - uni) / ea;
        const float cc = (f1 + f2) + f3;
        const bool inbc = (bm[g >> 5] >> (g & 31)) & 1u;
        float cost = cb;
        cost = cost + 0.33333334f * cc;
        cost = cost + (-giou);
        cost = cost + (inbc ? 0.0f : 100.0f);
        cost = cost + fgadd;
        ct[(size_t)gl * NQ] = cost;
    }
}

// ---------------- top-5 helpers (validated merge path) ----------------
template <bool MAXSEL>
__device__ __forceinline__ bool better(float av, int ai, float bv, int bi) {
    if (MAXSEL) return (av > bv) || (av == bv && ai < bi);
    else        return (av < bv) || (av == bv && ai < bi);
}

template <bool MAXSEL>
__device__ __forceinline__ void ins5(float (&v)[5], int (&id)[5], float nv, int ni) {
    if (!better<MAXSEL>(nv, ni, v[4], id[4])) return;
    v[4] = nv; id[4] = ni;
#pragma unroll
    for (int j = 4; j > 0; --j) {
        if (better<MAXSEL>(v[j], id[j], v[j - 1], id[j - 1])) {
            float tv = v[j]; v[j] = v[j - 1]; v[j - 1] = tv;
            int   ti = id[j]; id[j] = id[j - 1]; id[j - 1] = ti;
        }
    }
}

template <bool MAXSEL>
__device__ __forceinline__ void merge5(float (&v)[5], int (&id)[5], float (&ov)[5], int (&oi)[5]) {
#pragma unroll
    for (int r = 0; r < 5; ++r) {
        float bv = v[0]; int bi = id[0];
#pragma unroll
        for (int off = 32; off >= 1; off >>= 1) {
            float xv = __shfl_xor(bv, off, 64);
            int   xi = __shfl_xor(bi, off, 64);
            if (better<MAXSEL>(xv, xi, bv, bi)) { bv = xv; bi = xi; }
        }
        ov[r] = bv; oi[r] = bi;
        if (id[0] == bi) {
            v[0] = v[1]; id[0] = id[1];
            v[1] = v[2]; id[1] = id[2];
            v[2] = v[3]; id[2] = id[3];
            v[3] = v[4]; id[3] = id[4];
            v[4] = MAXSEL ? -INFINITY : INFINITY; id[4] = 0x7fffffff;
        }
    }
}

// ---------------- branchless 5-stage insertion networks (per-lane scan only) ----------------
// strict compares = first-seen-wins on ties; within a lane elements arrive in ascending q,
// so this matches ins5's (value, index) tie rule exactly. Lists stay sorted for merge5.
__device__ __forceinline__ void push_max5i(float (&v)[5], int (&id)[5], float t, int it) {
#pragma unroll
    for (int i = 0; i < 5; ++i) {
        const bool b = t > v[i];
        const float nv = b ? t : v[i];
        const float nt = b ? v[i] : t;
        const int ni  = b ? it : id[i];
        const int nit = b ? id[i] : it;
        v[i] = nv; id[i] = ni; t = nt; it = nit;
    }
}
__device__ __forceinline__ void push_min5i(float (&v)[5], int (&id)[5], float t, int it) {
#pragma unroll
    for (int i = 0; i < 5; ++i) {
        const bool b = t < v[i];
        const float nv = b ? t : v[i];
        const float nt = b ? v[i] : t;
        const int ni  = b ? it : id[i];
        const int nit = b ? id[i] : it;
        v[i] = nv; id[i] = ni; t = nt; it = nit;
    }
}

// ---------------- per-column top-5 (4 waves/column, branchless scan + validated merge) ----------------
#define CHUNK 1000   // NQ / 4
__global__ __launch_bounds__(256) void col_topk_kernel(
    const float* __restrict__ pb, const float* __restrict__ gbx, const float* __restrict__ costT,
    int* __restrict__ grc, int* __restrict__ grnew)
{
    const int g = blockIdx.x, b = blockIdx.y;
    const int tid = threadIdx.x, lane = tid & 63, wave = tid >> 6;   // 4 waves

    __shared__ float s_v[2][4][5];
    __shared__ int   s_i[2][4][5];

    const float gx0 = gbx[((size_t)b * NG + g) * 4 + 0];
    const float gy0 = gbx[((size_t)b * NG + g) * 4 + 1];
    const float gx1 = gbx[((size_t)b * NG + g) * 4 + 2];
    const float gy1 = gbx[((size_t)b * NG + g) * 4 + 3];
    const float areaB = (gx1 - gx0) * (gy1 - gy0);
    const float4* PB = reinterpret_cast<const float4*>(pb) + (size_t)b * NQ;
    const float* CT = costT + (size_t)b * NG * NQ + (size_t)g * NQ;

    const int q0 = wave * CHUNK, q1 = q0 + CHUNK;

    // IoU top-5 over this wave's chunk (branchless insert)
    {
        float tv[5]; int ti[5];
#pragma unroll
        for (int k = 0; k < 5; ++k) { tv[k] = -INFINITY; ti[k] = 0x7fffffff; }
        for (int base = q0; base < q1; base += 64) {
            const int q = base + lane;
            if (q < q1) {
                const float4 p = PB[q];
                const float ltx = fmaxf(p.x, gx0), lty = fmaxf(p.y, gy0);
                const float rbx = fminf(p.z, gx1), rby = fminf(p.w, gy1);
                const float iw = fmaxf(rbx - ltx, 0.0f), ih = fmaxf(rby - lty, 0.0f);
                const float inter = iw * ih;
                const float areaA = (p.z - p.x) * (p.w - p.y);
                const float uni = areaA + areaB - inter;
                push_max5i(tv, ti, inter / uni, q);
            }
        }
        float ov[5]; int oi[5];
        merge5<true>(tv, ti, ov, oi);
        if (lane == 0) {
#pragma unroll
            for (int k = 0; k < 5; ++k) { s_v[0][wave][k] = ov[k]; s_i[0][wave][k] = oi[k]; }
        }
    }

    // cost top-5 (min) over this wave's chunk (branchless insert)
    {
        float tv[5]; int ti[5];
#pragma unroll
        for (int k = 0; k < 5; ++k) { tv[k] = INFINITY; ti[k] = 0x7fffffff; }
        for (int base = q0; base < q1; base += 64) {
            const int q = base + lane;
            if (q < q1) push_min5i(tv, ti, CT[q], q);
        }
        float ov[5]; int oi[5];
        merge5<false>(tv, ti, ov, oi);
        if (lane == 0) {
#pragma unroll
            for (int k = 0; k < 5; ++k) { s_v[1][wave][k] = ov[k]; s_i[1][wave][k] = oi[k]; }
        }
    }
    __syncthreads();

    if (tid == 0) {
        float tv[5]; int ti[5];
#pragma unroll
        for (int k = 0; k < 5; ++k) { tv[k] = -INFINITY; ti[k] = 0x7fffffff; }
        for (int w = 0; w < 4; ++w)
#pragma unroll
            for (int k = 0; k < 5; ++k) ins5<true>(tv, ti, s_v[0][w][k], s_i[0][w][k]);
        const float s = ((((tv[0] + tv[1]) + tv[2]) + tv[3]) + tv[4]);
        int dk = (int)s;   // trunc toward zero, matches astype(int32)
        if (dk < 1) dk = 1;

        float cv[5]; int ci[5];
#pragma unroll
        for (int k = 0; k < 5; ++k) { cv[k] = INFINITY; ci[k] = 0x7fffffff; }
        for (int w = 0; w < 4; ++w)
#pragma unroll
            for (int k = 0; k < 5; ++k) ins5<false>(cv, ci, s_v[1][w][k], s_i[1][w][k]);

        for (int k = 0; k < dk; ++k) {
            atomicAdd(&grc[b * NQ + ci[k]], 1);
            grnew[b * NQ + ci[k]] = g;   // benign race: only read when grc==1
        }
    }
}

// replicate reference's sequential penalty accumulation rounding
__device__ __forceinline__ float pen_add(float v, int k) {
    while (k-- > 0) v += 100000.0f;
    return v;
}

__device__ __forceinline__ unsigned ordered_bits(float f) {
    unsigned u = __float_as_uint(f);
    return (u & 0x80000000u) ? ~u : (u | 0x80000000u);
}

// ---------------- match kernel: one block per image, only the sequential loop ----------------
__global__ __launch_bounds__(1024) void match_kernel(
    const float* __restrict__ costT, const int* __restrict__ grc, const int* __restrict__ grnew,
    float* __restrict__ out, int* __restrict__ rm_out)
{
    const int b = blockIdx.x, tid = threadIdx.x;
    const int lane = tid & 63, wave = tid >> 6;   // 16 waves

    __shared__ short              rmatch[NQ];
    __shared__ short              rnew[NQ];
    __shared__ unsigned short     pen[NQ];
    __shared__ int                rc[NQ];
    __shared__ int                colc[NG];
    __shared__ unsigned long long colkey[NG];
    __shared__ int                flag;

    const float* CT = costT + (size_t)b * NG * NQ;

    for (int q = tid; q < NQ; q += 1024) {
        rmatch[q] = -1;
        pen[q] = 0;
        rc[q] = grc[b * NQ + q];
        rnew[q] = (short)grnew[b * NQ + q];
    }
    __syncthreads();

    for (int iter = 0; iter < 2000; ++iter) {
        for (int q = tid; q < NQ; q += 1024) {
            const int oldm = rmatch[q];
            const int rcq  = rc[q];
            const int c    = rcq + (oldm >= 0 ? 1 : 0);
            int nm;
            if (c == 0) nm = -1;
            else if (c == 1) nm = rcq ? (int)rnew[q] : oldm;
            else {
                const int kp = pen[q];
                float bv = INFINITY; nm = 0;
                for (int g = 0; g < NG; ++g) {
                    const float v = pen_add(CT[(size_t)g * NQ + q], kp);
                    if (v < bv) { bv = v; nm = g; }
                }
            }
            rmatch[q] = (short)nm; rc[q] = 0;
        }
        __syncthreads();
        if (tid < NG) colc[tid] = 0;
        if (tid == 0) flag = 0;
        __syncthreads();
        for (int q = tid; q < NQ; q += 1024) { const int m = rmatch[q]; if (m >= 0) atomicAdd(&colc[m], 1); }
        __syncthreads();
        if (tid < NG && colc[tid] == 0) flag = 1;
        __syncthreads();
        if (!flag) break;

        for (int q = tid; q < NQ; q += 1024) { if (rmatch[q] >= 0) pen[q]++; }
        __syncthreads();
        for (int g = wave; g < NG; g += 16) {
            if (colc[g] != 0) continue;
            float bv = INFINITY; int bi = 0x7fffffff;
            for (int base = 0; base < NQ; base += 64) {
                const int q = base + lane;
                if (q < NQ) {
                    const float v = pen_add(CT[(size_t)g * NQ + q], (int)pen[q]);
                    if (v < bv || (v == bv && q < bi)) { bv = v; bi = q; }
                }
            }
#pragma unroll
            for (int off = 32; off >= 1; off >>= 1) {
                const float xv = __shfl_xor(bv, off, 64);
                const int   xi = __shfl_xor(bi, off, 64);
                if (xv < bv || (xv == bv && xi < bi)) { bv = xv; bi = xi; }
            }
            if (lane == 0) { atomicAdd(&rc[bi], 1); rnew[bi] = (short)g; }
        }
        __syncthreads();
    }

    // outputs: selected, gt_idx, rm; matched_qidx via per-row atomicMin (ordered-float<<32 | q)
    if (tid < NG) colkey[tid] = ~0ull;
    __syncthreads();
    for (int q = tid; q < NQ; q += 1024) {
        const int m = rmatch[q];
        out[OFF_SEL + (size_t)b * NQ + q] = (m >= 0) ? 1.0f : 0.0f;
        out[OFF_GTI + (size_t)b * NQ + q] = (float)(m >= 0 ? m : 0);
        rm_out[b * NQ + q] = m;
        if (m >= 0) {
            const float v = pen_add(CT[(size_t)m * NQ + q], (int)pen[q]);
            const unsigned long long key = ((unsigned long long)ordered_bits(v) << 32) | (unsigned)q;
            atomicMin(&colkey[m], key);
        }
    }
    __syncthreads();
    if (tid < NG) out[OFF_MQ + (size_t)b * NG + tid] = (float)(unsigned)(colkey[tid] & 0xffffffffull);
}

// ---------------- write-out: cost transpose + m expansion in one pass ----------------
__global__ __launch_bounds__(256) void write_out_kernel(
    const float* __restrict__ costT, const int* __restrict__ rm, float* __restrict__ out)
{
    const int b  = blockIdx.y;
    const int q0 = blockIdx.x * 64;
    __shared__ float tile[NG][65];
    __shared__ short srm[64];
    const float* CT = costT + (size_t)b * NG * NQ;
    for (int idx = threadIdx.x; idx < NG * 64; idx += 256) {
        const int g = idx >> 6, qi = idx & 63;
        const int q = q0 + qi;
        if (q < NQ) tile[g][qi] = CT[(size_t)g * NQ + q];
    }
    if (threadIdx.x < 64) {
        const int q = q0 + threadIdx.x;
        srm[threadIdx.x] = (q < NQ) ? (short)rm[b * NQ + q] : (short)-1;
    }
    __syncthreads();
    float* OC = out + OFF_COST + (size_t)b * NQ * NG;
    float* OM = out + OFF_M    + (size_t)b * NQ * NG;
    for (int idx = threadIdx.x; idx < 64 * NG; idx += 256) {
        const int qi = idx / NG, g = idx - qi * NG;
        const int q = q0 + qi;
        if (q < NQ) {
            OC[(size_t)q * NG + g] = tile[g][qi];
            OM[(size_t)q * NG + g] = (srm[qi] == g) ? 1.0f : 0.0f;
        }
    }
}

extern "C" void kernel_launch(void* const* d_in, const int* in_sizes, int n_in,
                              void* d_out, int out_size, void* d_ws, size_t ws_size,
                              hipStream_t stream)
{
    const float* l1  = (const float*)d_in[0];
    const float* l2  = (const float*)d_in[1];
    const float* l3  = (const float*)d_in[2];
    const float* pb  = (const float*)d_in[3];
    const float* gbx = (const float*)d_in[4];
    const float* img = (const float*)d_in[5];
    const int*   t1  = (const int*)d_in[6];
    const int*   t2  = (const int*)d_in[7];
    const int*   t3  = (const int*)d_in[8];
    float* out = (float*)d_out;

    char* ws = (char*)d_ws;
    float* costT = (float*)ws;                                   ws += (size_t)NB * NG * NQ * sizeof(float); // 51.2 MB
    int*   rm    = (int*)ws;                                     ws += (size_t)NB * NQ * sizeof(int);
    int*   grc   = (int*)ws;                                     ws += (size_t)NB * NQ * sizeof(int);
    int*   grnew = (int*)ws;                                     ws += (size_t)NB * NQ * sizeof(int);
    uint4* bmws  = (uint4*)ws;                                   ws += (size_t)NB * NQ * sizeof(uint4);
    float* fgws  = (float*)ws;

    // FDT scratch lives in the cost-output region: written by focal_kernel, consumed
    // by cost_kernel, then overwritten by write_out_kernel. 22.5 MB < 51.2 MB region.
    float* FDT = out + OFF_COST;

    hipMemsetAsync(grc, 0, (size_t)NB * NQ * sizeof(int), stream);

    dim3 fg((NQ + 63) / 64, NB);
    focal_kernel<<<fg, 256, 0, stream>>>(l1, l2, l3, FDT);

    dim3 mk((NQ + 255) / 256, NB);
    mask_kernel<<<mk, 256, 0, stream>>>(pb, gbx, bmws, fgws);

    dim3 cg((NQ + 255) / 256, NB, 4);
    cost_kernel<<<cg, 256, 0, stream>>>(pb, gbx, img, t1, t2, t3, FDT, bmws, fgws, costT);

    dim3 kg(NG, NB);
    col_topk_kernel<<<kg, 256, 0, stream>>>(pb, gbx, costT, grc, grnew);

    match_kernel<<<NB, 1024, 0, stream>>>(costT, grc, grnew, out, rm);

    dim3 wg((NQ + 63) / 64, NB);
    write_out_kernel<<<wg, 256, 0, stream>>>(costT, rm, out);
}